// Round 5
// baseline (479.775 us; speedup 1.0000x reference)
//
#include <hip/hip_runtime.h>
#include <hip/hip_bf16.h>

#define S_LEN  2048
#define BATCH  4
#define DIM    1024
#define NSTATE 256
#define DFF    2730
#define DFFP   2752              // K-padding for final GEMM (mult of 64)
#define DFQ    2816              // row-padding for w1/w2 (mult of 128)
#define NROWS  (BATCH * S_LEN)   // 8192
#define LC     16                // scan chunk length (r4 win: 2 blocks/CU)
#define WARM   32                // scan warm-up window (decay ~e^-13 worst)
#define NBG    384               // WB(256) + Wg(32) + zero pad(96)
#define FFN_NT (DIM / 64)        // 16 K-tiles in the 8-phase ffn GEMM

typedef __attribute__((ext_vector_type(8))) short bf16x8;
typedef __attribute__((ext_vector_type(4))) float f32x4;

__device__ __forceinline__ float bf2f(ushort u) {
    return __uint_as_float(((unsigned int)u) << 16);
}
__device__ __forceinline__ ushort f2bf(float f) {
    unsigned int u = __float_as_uint(f);
    u += 0x7fffu + ((u >> 16) & 1u);   // RNE
    return (ushort)(u >> 16);
}

// async global->LDS, 16B per lane. LDS dest is wave-uniform base + lane*16.
__device__ __forceinline__ void gld_lds16(const ushort* g, ushort* l) {
    __builtin_amdgcn_global_load_lds(
        (const __attribute__((address_space(1))) unsigned int*)g,
        (__attribute__((address_space(3))) unsigned int*)l,
        16, 0, 0);
}

// ---------------------------------------------------------------------------
// fp32 -> bf16 converter (n4 = n/4), grid-stride
// ---------------------------------------------------------------------------
__global__ __launch_bounds__(256) void f2b_kernel(
    const float* __restrict__ src, ushort* __restrict__ dst, int n4)
{
    for (int i = blockIdx.x * 256 + threadIdx.x; i < n4; i += gridDim.x * 256) {
        float4 v = *(const float4*)(src + i * 4);
        ushort4 o;
        o.x = f2bf(v.x); o.y = f2bf(v.y); o.z = f2bf(v.z); o.w = f2bf(v.w);
        *(ushort4*)(dst + i * 4) = o;
    }
}

// W12 interleave: dst row r = (r&1 ? w2 : w1)[r>>1] -> bf16, zeros past DFF
__global__ __launch_bounds__(256) void pack_w12_kernel(
    const float* __restrict__ w1, const float* __restrict__ w2,
    ushort* __restrict__ dst)
{
    const int row = blockIdx.x, t = threadIdx.x;
    const int srow = row >> 1;
    const float* src = (row & 1) ? w2 : w1;
    ushort4 o = {0, 0, 0, 0};
    if (srow < DFF) {
        float4 v = *(const float4*)(src + (size_t)srow * DIM + t * 4);
        o.x = f2bf(v.x); o.y = f2bf(v.y); o.z = f2bf(v.z); o.w = f2bf(v.w);
    }
    *(ushort4*)(dst + (size_t)row * DIM + t * 4) = o;
}

// WBG = [WB (256 x 1024); Wg (32 x 1024); zeros (96 x 1024)] -> bf16
__global__ __launch_bounds__(256) void pack_wbg_kernel(
    const float* __restrict__ WB, const float* __restrict__ Wg,
    ushort* __restrict__ dst)
{
    const int row = blockIdx.x, t = threadIdx.x;
    ushort4 o = {0, 0, 0, 0};
    const float* src = nullptr;
    if (row < NSTATE) src = WB + (size_t)row * DIM;
    else if (row < NSTATE + 32) src = Wg + (size_t)(row - NSTATE) * DIM;
    if (src) {
        float4 v = *(const float4*)(src + t * 4);
        o.x = f2bf(v.x); o.y = f2bf(v.y); o.z = f2bf(v.z); o.w = f2bf(v.w);
    }
    *(ushort4*)(dst + (size_t)row * DIM + t * 4) = o;
}

// w3 (DIM x DFF) fp32 -> bf16 padded to (DIM x DFFP), zero tail
__global__ __launch_bounds__(256) void pad_w3_kernel(
    const float* __restrict__ w3, ushort* __restrict__ w3p)
{
    const int col = blockIdx.x * 256 + threadIdx.x;
    const int row = blockIdx.y;
    if (col >= DFFP) return;
    ushort v = 0;
    if (col < DFF) v = f2bf(w3[(size_t)row * DFF + col]);
    w3p[(size_t)row * DFFP + col] = v;
}

// ---------------------------------------------------------------------------
// Cayley: Q = (I+A)^-1 (I-A), A = S - S^T, 16x16, 32 matrices (0..15=L, 16..31=R)
// ---------------------------------------------------------------------------
__global__ __launch_bounds__(256) void cayley_kernel(
    const float* __restrict__ Lsk, const float* __restrict__ Rsk,
    float* __restrict__ QL, float* __restrict__ QR)
{
    __shared__ float Ms[16][17];
    __shared__ float Rh[16][17];
    const int m = blockIdx.x;
    const float* src = (m < 16) ? (Lsk + m * 256) : (Rsk + (m - 16) * 256);
    const int t = threadIdx.x;
    const int i = t >> 4, j = t & 15;
    float a = src[i * 16 + j] - src[j * 16 + i];
    float eye = (i == j) ? 1.f : 0.f;
    Ms[i][j] = eye + a;
    Rh[i][j] = eye - a;
    __syncthreads();
    for (int k = 0; k < 16; ++k) {
        float f = Ms[i][k] / Ms[k][k];
        __syncthreads();
        if (i != k) {
            Ms[i][j] -= f * Ms[k][j];
            Rh[i][j] -= f * Rh[k][j];
        }
        __syncthreads();
    }
    float q = Rh[i][j] / Ms[i][i];
    float* dst = (m < 16) ? (QL + m * 256) : (QR + (m - 16) * 256);
    dst[i * 16 + j] = q;
}

// ---------------------------------------------------------------------------
// rmsnorm: out_bf16 = bf16(w * in / rms), fp32 input (used for both norms)
// ---------------------------------------------------------------------------
__global__ __launch_bounds__(256) void rms_kernel(
    const float* __restrict__ xin, const float* __restrict__ nw,
    ushort* __restrict__ xo)
{
    __shared__ float part[4];
    __shared__ float invs;
    const int row = blockIdx.x, t = threadIdx.x;
    float4 xv = *(const float4*)(xin + (size_t)row * DIM + t * 4);
    float ss = xv.x * xv.x + xv.y * xv.y + xv.z * xv.z + xv.w * xv.w;
    for (int off = 32; off > 0; off >>= 1) ss += __shfl_down(ss, off, 64);
    if ((t & 63) == 0) part[t >> 6] = ss;
    __syncthreads();
    if (t == 0) {
        float tot = part[0] + part[1] + part[2] + part[3];
        invs = 1.f / sqrtf(tot / (float)DIM + 1e-6f);
    }
    __syncthreads();
    float inv = invs;
    float4 wv = *(const float4*)(nw + t * 4);
    ushort4 ov;
    ov.x = f2bf(wv.x * xv.x * inv);
    ov.y = f2bf(wv.y * xv.y * inv);
    ov.z = f2bf(wv.z * xv.z * inv);
    ov.w = f2bf(wv.w * xv.w * inv);
    *(ushort4*)(xo + (size_t)row * DIM + t * 4) = ov;
}

// ---------------------------------------------------------------------------
// Windowed parallel scan. LC=16 -> 512 blocks = 2/CU (r4: -22us).
// ---------------------------------------------------------------------------
__global__ __launch_bounds__(256) void scan_win_kernel(
    const float* __restrict__ QL, const float* __restrict__ QR,
    const float* __restrict__ gates, const float* __restrict__ Bx,
    ushort* __restrict__ hs)
{
    __shared__ float Hs[256];
    __shared__ float Us[256];
    const int chunk = blockIdx.x, b = blockIdx.y, t = threadIdx.x;
    const int hi = t >> 4, lo = t & 15;
    float Rrow[16], Lrow[16];
    #pragma unroll
    for (int k = 0; k < 16; ++k) {
        Rrow[k] = QR[hi * 256 + lo * 16 + k];   // R_Q[j=hi][i=lo][k]
        Lrow[k] = QL[lo * 256 + hi * 16 + k];   // L_Q[c=lo][r=hi][k]
    }
    Hs[t] = 0.f;
    __syncthreads();
    const int wstart = chunk * LC;
    const int s0 = (wstart >= WARM) ? (wstart - WARM) : 0;
    const int send = wstart + LC;
    const float* gb = gates + (size_t)b * S_LEN * 32;
    const float* xb = Bx + (size_t)b * S_LEN * NSTATE;
    ushort* hb = hs + (size_t)b * S_LEN * NSTATE;
    float beta  = gb[s0 * 32 + 16 + hi];
    float alpha = gb[s0 * 32 + lo];
    float bx    = xb[s0 * NSTATE + t];
    for (int s = s0; s < send; ++s) {
        float betaN = 0.f, alphaN = 0.f, bxN = 0.f;
        if (s + 1 < send) {
            betaN  = gb[(s + 1) * 32 + 16 + hi];
            alphaN = gb[(s + 1) * 32 + lo];
            bxN    = xb[(s + 1) * NSTATE + t];
        }
        float acc = 0.f;
        #pragma unroll
        for (int k = 0; k < 16; ++k) acc += Rrow[k] * Hs[hi * 16 + k];
        Us[t] = beta * acc;
        __syncthreads();
        float acc2 = 0.f;
        #pragma unroll
        for (int k = 0; k < 16; ++k) acc2 += Lrow[k] * Us[k * 16 + lo];
        float h = alpha * acc2 + bx;
        Hs[t] = h;
        if (s >= wstart) hb[s * NSTATE + t] = f2bf(h);
        beta = betaN; alpha = alphaN; bx = bxN;
        __syncthreads();
    }
}

// ---------------------------------------------------------------------------
// Async GEMM: C(MxN) = A(MxK)*B(NxK)^T [+bias +resF] -> fp32.
// 128x128 tile, BK=64, XOR-8 LDS swizzle, 4 waves (2x2 of 64x64),
// 16x16x32 bf16 MFMA, global_load_lds width-16 staging.
// ---------------------------------------------------------------------------
__global__ __launch_bounds__(256) void gemm_async(
    const ushort* __restrict__ A, int lda,
    const ushort* __restrict__ B, int ldb,
    int K, int ldc,
    const float* __restrict__ bias,
    const float* __restrict__ resF,
    float* __restrict__ outF)
{
    __shared__ ushort As[128 * 64];
    __shared__ ushort Bs[128 * 64];
    const int tid = threadIdx.x;
    const int m0 = blockIdx.y * 128, n0 = blockIdx.x * 128;
    const int w = tid >> 6, lane = tid & 63;
    const int wm = (w >> 1) * 64, wn = (w & 1) * 64;
    const int lr = lane & 15, quad = lane >> 4;
    const int rx = lr & 7;   // reader XOR key (row&7 of every frag row)
    f32x4 acc[4][4];
    #pragma unroll
    for (int i = 0; i < 4; ++i)
        #pragma unroll
        for (int j = 0; j < 4; ++j) acc[i][j] = (f32x4){0.f, 0.f, 0.f, 0.f};
    const int srow = tid >> 3;                              // 0..31
    const int scol = (((tid & 7) ^ (srow & 7)) * 8);        // swizzled fetch col
    const ushort* ga = A + (size_t)(m0 + srow) * lda + scol;
    const ushort* gb = B + (size_t)(n0 + srow) * ldb + scol;
    for (int kt = 0; kt < K; kt += 64) {
        #pragma unroll
        for (int p = 0; p < 4; ++p) {
            gld_lds16(ga + (size_t)(p * 32) * lda + kt, &As[p * 2048 + tid * 8]);
            gld_lds16(gb + (size_t)(p * 32) * ldb + kt, &Bs[p * 2048 + tid * 8]);
        }
        __syncthreads();
        #pragma unroll
        for (int s = 0; s < 2; ++s) {
            const int cg = ((s * 4 + quad) ^ rx) * 8;
            bf16x8 af[4], bfr[4];
            #pragma unroll
            for (int f = 0; f < 4; ++f) {
                af[f]  = *(const bf16x8*)&As[(wm + f * 16 + lr) * 64 + cg];
                bfr[f] = *(const bf16x8*)&Bs[(wn + f * 16 + lr) * 64 + cg];
            }
            #pragma unroll
            for (int i = 0; i < 4; ++i)
                #pragma unroll
                for (int j = 0; j < 4; ++j)
                    acc[i][j] = __builtin_amdgcn_mfma_f32_16x16x32_bf16(
                        af[i], bfr[j], acc[i][j], 0, 0, 0);
        }
        __syncthreads();
    }
    #pragma unroll
    for (int i = 0; i < 4; ++i) {
        int row = m0 + wm + i * 16 + quad * 4;
        #pragma unroll
        for (int j = 0; j < 4; ++j) {
            int col = n0 + wn + j * 16 + lr;
            float bv = bias ? bias[col] : 0.f;
            #pragma unroll
            for (int r = 0; r < 4; ++r) {
                size_t idx = (size_t)(row + r) * ldc + col;
                float v = acc[i][j][r] + bv;
                if (resF) v += resF[idx];
                outF[idx] = v;
            }
        }
    }
}

// ---------------------------------------------------------------------------
// Merged Bx+gates GEMM: [Bx | gate-logits] = xs @ WBG^T, N=384, BK=64+swizzle.
// ---------------------------------------------------------------------------
__global__ __launch_bounds__(256) void gemm_bxg(
    const ushort* __restrict__ A,     // xs: NROWS x DIM
    const ushort* __restrict__ WBG,   // NBG x DIM
    const float* __restrict__ bB, const float* __restrict__ bg,
    float* __restrict__ Bx, float* __restrict__ gates)
{
    __shared__ ushort As[128 * 64];
    __shared__ ushort Bs[128 * 64];
    const int tid = threadIdx.x;
    const int m0 = blockIdx.y * 128, n0 = blockIdx.x * 128;
    const int w = tid >> 6, lane = tid & 63;
    const int wm = (w >> 1) * 64, wn = (w & 1) * 64;
    const int lr = lane & 15, quad = lane >> 4;
    const int rx = lr & 7;
    f32x4 acc[4][4];
    #pragma unroll
    for (int i = 0; i < 4; ++i)
        #pragma unroll
        for (int j = 0; j < 4; ++j) acc[i][j] = (f32x4){0.f, 0.f, 0.f, 0.f};
    const int srow = tid >> 3;
    const int scol = (((tid & 7) ^ (srow & 7)) * 8);
    const ushort* ga = A   + (size_t)(m0 + srow) * DIM + scol;
    const ushort* gb = WBG + (size_t)(n0 + srow) * DIM + scol;
    for (int kt = 0; kt < DIM; kt += 64) {
        #pragma unroll
        for (int p = 0; p < 4; ++p) {
            gld_lds16(ga + (size_t)(p * 32) * DIM + kt, &As[p * 2048 + tid * 8]);
            gld_lds16(gb + (size_t)(p * 32) * DIM + kt, &Bs[p * 2048 + tid * 8]);
        }
        __syncthreads();
        #pragma unroll
        for (int s = 0; s < 2; ++s) {
            const int cg = ((s * 4 + quad) ^ rx) * 8;
            bf16x8 af[4], bfr[4];
            #pragma unroll
            for (int f = 0; f < 4; ++f) {
                af[f]  = *(const bf16x8*)&As[(wm + f * 16 + lr) * 64 + cg];
                bfr[f] = *(const bf16x8*)&Bs[(wn + f * 16 + lr) * 64 + cg];
            }
            #pragma unroll
            for (int i = 0; i < 4; ++i)
                #pragma unroll
                for (int j = 0; j < 4; ++j)
                    acc[i][j] = __builtin_amdgcn_mfma_f32_16x16x32_bf16(
                        af[i], bfr[j], acc[i][j], 0, 0, 0);
        }
        __syncthreads();
    }
    #pragma unroll
    for (int i = 0; i < 4; ++i) {
        int row = m0 + wm + i * 16 + quad * 4;
        #pragma unroll
        for (int j = 0; j < 4; ++j) {
            int col = n0 + wn + j * 16 + lr;
            #pragma unroll
            for (int r = 0; r < 4; ++r) {
                float v = acc[i][j][r];
                if (col < NSTATE) {
                    Bx[(size_t)(row + r) * NSTATE + col] = v + bB[col];
                } else if (col < NSTATE + 32) {
                    int g = col - NSTATE;
                    gates[(size_t)(row + r) * 32 + g] =
                        1.f / (1.f + expf(-(v + bg[g])));
                }
            }
        }
    }
}

// ---------------------------------------------------------------------------
// 8-phase-style 256x256 FFN GEMM, v3 (m201-faithful): C = xn @ W12^T,
// epilogue shfl_xor(1) -> pb = bf16(silu(v1)*v2).
//
// r2/r3 post-mortem: holding all 4 operand halves live (96 VGPR) + acc(128)
// blew the register budget -> remat (r2) / scratch spills (r3). v3 re-reads
// from LDS per phase so peak frag liveness is ONE A-half(32) + ONE B-half(16).
// Zigzag phase order (0,0)->(0,1)->(1,1)->(1,0): each phase reads only the
// NEW half (8 or 4 ds_read_b128); only B-half0 is read twice per tile.
//
// Staging halves are interleaved row-groups so every wave's phase-k reads lie
// in the half with deadline k: hA0 = rows 0-63,128-191; hA1 = 64-127,192-255;
// hB0 = 32-row groups 0,2,4,6; hB1 = groups 1,3,5,7.
// Issue (tile t): P1 stage hA0(t+1), P2 hB0(t+1), P3 hB1(t+1), P4 hA1(t+1).
// Deadlines: tau.P1 needs hA0,hB0(tau); tau.P2 needs hB1; tau.P3 needs hA1.
// vmcnt algebra (2 gloads/STAGE, end-of-phase wait BEFORE s_barrier):
//   end P1: outstanding 6, need oldest 2 -> vmcnt(4)   [tail tile: vmcnt(2)]
//   end P2: outstanding 6, need oldest 2 -> vmcnt(4)   [tail: vmcnt(0)]
//   end P3: nothing to protect           -> no wait
//   end P4: outstanding 8, need oldest 4 -> vmcnt(4)   [tail: none]
// Never vmcnt(0) mid-loop. asm "memory" clobber after each barrier pins
// hoisting of next phase's plain-C++ ds_reads.
// ---------------------------------------------------------------------------
__global__ __launch_bounds__(512, 2) void ffn_gemm8(
    const ushort* __restrict__ A,     // xn: NROWS x DIM
    const ushort* __restrict__ W12,   // (2*DFQ) x DIM, row-interleaved w1/w2
    ushort* __restrict__ pb)          // NROWS x DFFP
{
    __shared__ ushort sm[65536];      // 128 KiB: 2 x (A 256x64 | B 256x64)
    const int tid = threadIdx.x;
    const int m0 = blockIdx.y * 256, n0 = blockIdx.x * 256;
    const int wid = tid >> 6, lane = tid & 63;
    const int wr = wid >> 2, wc = wid & 3;     // wave grid 2(M) x 4(N)
    const int lr = lane & 15, quad = lane >> 4;
    const int rx = lr & 7;
    const int srow = tid >> 3;                 // 0..63 (staging row in 64-blk)
    const int scol = ((tid & 7) ^ (srow & 7)) * 8;
    const int t7x8 = (tid & 7) * 8;

    f32x4 acc[8][4];
    #pragma unroll
    for (int i = 0; i < 8; ++i)
        #pragma unroll
        for (int j = 0; j < 4; ++j) acc[i][j] = (f32x4){0.f, 0.f, 0.f, 0.f};

    // stage one interleaved A-half (2 gloads): rows srow+half*64 and +128
    auto STAGE_A = [&](int pi, int half, int t) {
        #pragma unroll
        for (int c = 0; c < 2; ++c) {
            const int mrow = srow + half * 64 + c * 128;
            gld_lds16(A + (size_t)(m0 + mrow) * DIM + t * 64 + scol,
                      &sm[pi * 32768 + mrow * 64 + t7x8]);
        }
    };
    // stage one interleaved B-half (2 gloads): 32-row groups
    auto STAGE_B = [&](int pi, int half, int t) {
        #pragma unroll
        for (int c = 0; c < 2; ++c) {
            const int mrow = (srow & 31) + ((srow >> 5) * 64) + half * 32 + c * 128;
            gld_lds16(W12 + (size_t)(n0 + mrow) * DIM + t * 64 + scol,
                      &sm[pi * 32768 + 16384 + mrow * 64 + t7x8]);
        }
    };
    const int aRdBase = wr * 128 * 64;
    const int bRdBase = 16384 + wc * 64 * 64;
    const int cg0 = (quad ^ rx) * 8;
    const int cg1 = ((4 + quad) ^ rx) * 8;
    auto LDA = [&](bf16x8 (*d)[2], int half, int pib) {
        #pragma unroll
        for (int f = 0; f < 4; ++f) {
            const int ro = pib + aRdBase + (half * 64 + f * 16 + lr) * 64;
            d[f][0] = *(const bf16x8*)&sm[ro + cg0];
            d[f][1] = *(const bf16x8*)&sm[ro + cg1];
        }
    };
    auto LDB = [&](bf16x8 (*d)[2], int half, int pib) {
        #pragma unroll
        for (int g = 0; g < 2; ++g) {
            const int ro = pib + bRdBase + (half * 32 + g * 16 + lr) * 64;
            d[g][0] = *(const bf16x8*)&sm[ro + cg0];
            d[g][1] = *(const bf16x8*)&sm[ro + cg1];
        }
    };

    // prologue: tile0 halves in deadline order hA0,hB0,hB1,hA1 (8 gloads)
    STAGE_A(0, 0, 0); STAGE_B(0, 0, 0); STAGE_B(0, 1, 0); STAGE_A(0, 1, 0);
    asm volatile("s_waitcnt vmcnt(4)");    // hA0,hB0 landed
    __builtin_amdgcn_s_barrier();
    asm volatile("" ::: "memory");

    bf16x8 af[4][2], bf[2][2];

    #pragma unroll 2
    for (int t = 0; t < FFN_NT; ++t) {
        const int pib = (t & 1) * 32768;
        const int qib = pib ^ 32768;
        const bool more = (t + 1 < FFN_NT);
        // ---- P1: quadrant (mh0,nh0); read A0+B0; stage hA0(t+1)
        LDA(af, 0, pib);
        LDB(bf, 0, pib);
        if (more) STAGE_A(qib >> 15, 0, t + 1);
        __builtin_amdgcn_s_setprio(1);
        #pragma unroll
        for (int f = 0; f < 4; ++f)
            #pragma unroll
            for (int g = 0; g < 2; ++g) {
                acc[f][g] = __builtin_amdgcn_mfma_f32_16x16x32_bf16(
                    af[f][0], bf[g][0], acc[f][g], 0, 0, 0);
                acc[f][g] = __builtin_amdgcn_mfma_f32_16x16x32_bf16(
                    af[f][1], bf[g][1], acc[f][g], 0, 0, 0);
            }
        __builtin_amdgcn_s_setprio(0);
        if (more) asm volatile("s_waitcnt vmcnt(4)");
        else      asm volatile("s_waitcnt vmcnt(2)");
        __builtin_amdgcn_s_barrier();
        asm volatile("" ::: "memory");
        // ---- P2: quadrant (0,1); read B1 (A0 stays); stage hB0(t+1)
        LDB(bf, 1, pib);
        if (more) STAGE_B(qib >> 15, 0, t + 1);
        __builtin_amdgcn_s_setprio(1);
        #pragma unroll
        for (int f = 0; f < 4; ++f)
            #pragma unroll
            for (int g = 0; g < 2; ++g) {
                acc[f][2 + g] = __builtin_amdgcn_mfma_f32_16x16x32_bf16(
                    af[f][0], bf[g][0], acc[f][2 + g], 0, 0, 0);
                acc[f][2 + g] = __builtin_amdgcn_mfma_f32_16x16x32_bf16(
                    af[f][1], bf[g][1], acc[f][2 + g], 0, 0, 0);
            }
        __builtin_amdgcn_s_setprio(0);
        if (more) asm volatile("s_waitcnt vmcnt(4)");
        else      asm volatile("s_waitcnt vmcnt(0)");
        __builtin_amdgcn_s_barrier();
        asm volatile("" ::: "memory");
        // ---- P3: quadrant (1,1); read A1 (B1 stays); stage hB1(t+1)
        LDA(af, 1, pib);
        if (more) STAGE_B(qib >> 15, 1, t + 1);
        __builtin_amdgcn_s_setprio(1);
        #pragma unroll
        for (int f = 0; f < 4; ++f)
            #pragma unroll
            for (int g = 0; g < 2; ++g) {
                acc[4 + f][2 + g] = __builtin_amdgcn_mfma_f32_16x16x32_bf16(
                    af[f][0], bf[g][0], acc[4 + f][2 + g], 0, 0, 0);
                acc[4 + f][2 + g] = __builtin_amdgcn_mfma_f32_16x16x32_bf16(
                    af[f][1], bf[g][1], acc[4 + f][2 + g], 0, 0, 0);
            }
        __builtin_amdgcn_s_setprio(0);
        __builtin_amdgcn_s_barrier();            // no vmcnt needed here
        asm volatile("" ::: "memory");
        // ---- P4: quadrant (1,0); re-read B0 (A1 stays); stage hA1(t+1)
        LDB(bf, 0, pib);
        if (more) STAGE_A(qib >> 15, 1, t + 1);
        __builtin_amdgcn_s_setprio(1);
        #pragma unroll
        for (int f = 0; f < 4; ++f)
            #pragma unroll
            for (int g = 0; g < 2; ++g) {
                acc[4 + f][g] = __builtin_amdgcn_mfma_f32_16x16x32_bf16(
                    af[f][0], bf[g][0], acc[4 + f][g], 0, 0, 0);
                acc[4 + f][g] = __builtin_amdgcn_mfma_f32_16x16x32_bf16(
                    af[f][1], bf[g][1], acc[4 + f][g], 0, 0, 0);
            }
        __builtin_amdgcn_s_setprio(0);
        if (more) {
            asm volatile("s_waitcnt vmcnt(4)");
            __builtin_amdgcn_s_barrier();
            asm volatile("" ::: "memory");
        }
    }

    // epilogue: pair adjacent columns (v1 even, v2 odd) via shfl_xor(1)
    #pragma unroll
    for (int i = 0; i < 8; ++i) {
        const int row = m0 + wr * 128 + i * 16 + quad * 4;
        #pragma unroll
        for (int j = 0; j < 4; ++j) {
            const int col = n0 + wc * 64 + j * 16 + lr;
            #pragma unroll
            for (int r = 0; r < 4; ++r) {
                float v  = acc[i][j][r];
                float vp = __shfl_xor(v, 1, 64);
                if (!(lr & 1)) {
                    const int oc = col >> 1;
                    if (oc < DFFP) {
                        float p = v / (1.f + expf(-v)) * vp;
                        pb[(size_t)(row + r) * DFFP + oc] = f2bf(p);
                    }
                }
            }
        }
    }
}

// ---------------------------------------------------------------------------
extern "C" void kernel_launch(void* const* d_in, const int* in_sizes, int n_in,
                              void* d_out, int out_size, void* d_ws, size_t ws_size,
                              hipStream_t stream) {
    const float* x   = (const float*)d_in[0];
    const float* Lsk = (const float*)d_in[1];
    const float* Rsk = (const float*)d_in[2];
    const float* Wg  = (const float*)d_in[3];
    const float* bg  = (const float*)d_in[4];
    const float* WB  = (const float*)d_in[5];
    const float* bB  = (const float*)d_in[6];
    const float* WC  = (const float*)d_in[7];
    const float* bC  = (const float*)d_in[8];
    const float* n1w = (const float*)d_in[9];
    const float* n2w = (const float*)d_in[10];
    const float* w1  = (const float*)d_in[11];
    const float* w2  = (const float*)d_in[12];
    const float* w3  = (const float*)d_in[13];
    float* out = (float*)d_out;

    char* wp = (char*)d_ws;
    auto carve = [&](size_t bytes) -> char* {
        char* p = wp;
        wp += (bytes + 255) & ~(size_t)255;
        return p;
    };
    float*  QL    = (float*)carve(16 * 256 * 4);
    float*  QR    = (float*)carve(16 * 256 * 4);
    ushort* WBGb  = (ushort*)carve((size_t)NBG * DIM * 2);
    ushort* WCb   = (ushort*)carve((size_t)DIM * NSTATE * 2);
    ushort* w12   = (ushort*)carve((size_t)2 * DFQ * DIM * 2);
    ushort* w3p   = (ushort*)carve((size_t)DIM * DFFP * 2);
    ushort* xs    = (ushort*)carve((size_t)NROWS * DIM * 2);
    float*  x2    = (float*)carve((size_t)NROWS * DIM * 4);
    ushort* pb    = (ushort*)carve((size_t)NROWS * DFFP * 2);
    char*   scr   = carve((size_t)16 << 20);                // gates/Bx/hs region
    float*  gates = (float*)scr;                            // 1.05 MB
    float*  Bx    = (float*)(scr + (1 << 21));              // 8.39 MB @ +2MB
    ushort* hs    = (ushort*)(scr + (11u << 20));           // 4.19 MB @ +11MB
    ushort* xn    = xs;   // xs dead after bxg GEMM; reuse as xn

    cayley_kernel<<<32, 256, 0, stream>>>(Lsk, Rsk, QL, QR);
    pack_wbg_kernel<<<NBG, 256, 0, stream>>>(WB, Wg, WBGb);
    f2b_kernel<<<256, 256, 0, stream>>>(WC, WCb, DIM * NSTATE / 4);
    pack_w12_kernel<<<2 * DFQ, 256, 0, stream>>>(w1, w2, w12);
    pad_w3_kernel<<<dim3(11, DIM), 256, 0, stream>>>(w3, w3p);
    // xs = rmsnorm(x, n1w)
    rms_kernel<<<NROWS, 256, 0, stream>>>(x, n1w, xs);
    // [Bx | gates] = xs @ WBG^T (+bB | sigmoid(+bg))
    gemm_bxg<<<dim3(3, 64), 256, 0, stream>>>(xs, WBGb, bB, bg, Bx, gates);
    scan_win_kernel<<<dim3(S_LEN / LC, BATCH), 256, 0, stream>>>(QL, QR, gates, Bx, hs);
    // x2 = hs @ WC^T + bC + x  -> fp32
    gemm_async<<<dim3(8, 64), 256, 0, stream>>>(hs, NSTATE, WCb, NSTATE, NSTATE, DIM,
                                                bC, x, x2);
    // xn = rmsnorm(x2, n2w)
    rms_kernel<<<NROWS, 256, 0, stream>>>(x2, n2w, xn);
    // pb = silu(xn@w1^T) * (xn@w2^T)  (8-phase v3, interleaved W12)
    ffn_gemm8<<<dim3(2 * DFQ / 256, NROWS / 256), 512, 0, stream>>>(xn, w12, pb);
    // out = pb @ w3p^T + x2  -> fp32 (d_out)
    gemm_async<<<dim3(8, 64), 256, 0, stream>>>(pb, DFFP, w3p, DFFP, DFFP, DIM,
                                                nullptr, x2, out);
}

// Round 6
// 430.790 us; speedup vs baseline: 1.1137x; 1.1137x over previous
//
#include <hip/hip_runtime.h>
#include <hip/hip_bf16.h>

#define S_LEN  2048
#define BATCH  4
#define DIM    1024
#define NSTATE 256
#define DFF    2730
#define DFFP   2752              // K-padding for final GEMM (mult of 64)
#define DFQ    2816              // row-padding for w1/w2 (mult of 128)
#define NROWS  (BATCH * S_LEN)   // 8192
#define LC     16                // scan chunk length (r4 win: 2 blocks/CU)
#define WARM   32                // scan warm-up window (decay ~e^-13 worst)
#define NBG    384               // WB(256) + Wg(32) + zero pad(96)

typedef __attribute__((ext_vector_type(8))) short bf16x8;
typedef __attribute__((ext_vector_type(4))) float f32x4;

__device__ __forceinline__ float bf2f(ushort u) {
    return __uint_as_float(((unsigned int)u) << 16);
}
__device__ __forceinline__ ushort f2bf(float f) {
    unsigned int u = __float_as_uint(f);
    u += 0x7fffu + ((u >> 16) & 1u);   // RNE
    return (ushort)(u >> 16);
}

// async global->LDS, 16B per lane. LDS dest is wave-uniform base + lane*16.
__device__ __forceinline__ void gld_lds16(const ushort* g, ushort* l) {
    __builtin_amdgcn_global_load_lds(
        (const __attribute__((address_space(1))) unsigned int*)g,
        (__attribute__((address_space(3))) unsigned int*)l,
        16, 0, 0);
}

// ---------------------------------------------------------------------------
// fp32 -> bf16 converter (n4 = n/4), grid-stride
// ---------------------------------------------------------------------------
__global__ __launch_bounds__(256) void f2b_kernel(
    const float* __restrict__ src, ushort* __restrict__ dst, int n4)
{
    for (int i = blockIdx.x * 256 + threadIdx.x; i < n4; i += gridDim.x * 256) {
        float4 v = *(const float4*)(src + i * 4);
        ushort4 o;
        o.x = f2bf(v.x); o.y = f2bf(v.y); o.z = f2bf(v.z); o.w = f2bf(v.w);
        *(ushort4*)(dst + i * 4) = o;
    }
}

// src (rows_src x 1024) fp32 -> dst (gridDim.x x 1024) bf16, zero pad rows
__global__ __launch_bounds__(256) void f2b_padrow_kernel(
    const float* __restrict__ src, ushort* __restrict__ dst, int rows_src)
{
    const int row = blockIdx.x, t = threadIdx.x;
    ushort4 o = {0, 0, 0, 0};
    if (row < rows_src) {
        float4 v = *(const float4*)(src + (size_t)row * DIM + t * 4);
        o.x = f2bf(v.x); o.y = f2bf(v.y); o.z = f2bf(v.z); o.w = f2bf(v.w);
    }
    *(ushort4*)(dst + (size_t)row * DIM + t * 4) = o;
}

// WBG = [WB (256 x 1024); Wg (32 x 1024); zeros (96 x 1024)] -> bf16
__global__ __launch_bounds__(256) void pack_wbg_kernel(
    const float* __restrict__ WB, const float* __restrict__ Wg,
    ushort* __restrict__ dst)
{
    const int row = blockIdx.x, t = threadIdx.x;
    ushort4 o = {0, 0, 0, 0};
    const float* src = nullptr;
    if (row < NSTATE) src = WB + (size_t)row * DIM;
    else if (row < NSTATE + 32) src = Wg + (size_t)(row - NSTATE) * DIM;
    if (src) {
        float4 v = *(const float4*)(src + t * 4);
        o.x = f2bf(v.x); o.y = f2bf(v.y); o.z = f2bf(v.z); o.w = f2bf(v.w);
    }
    *(ushort4*)(dst + (size_t)row * DIM + t * 4) = o;
}

// w3 (DIM x DFF) fp32 -> bf16 padded to (DIM x DFFP), zero tail
__global__ __launch_bounds__(256) void pad_w3_kernel(
    const float* __restrict__ w3, ushort* __restrict__ w3p)
{
    const int col = blockIdx.x * 256 + threadIdx.x;
    const int row = blockIdx.y;
    if (col >= DFFP) return;
    ushort v = 0;
    if (col < DFF) v = f2bf(w3[(size_t)row * DFF + col]);
    w3p[(size_t)row * DFFP + col] = v;
}

// ---------------------------------------------------------------------------
// Cayley: Q = (I+A)^-1 (I-A), A = S - S^T, 16x16, 32 matrices (0..15=L, 16..31=R)
// ---------------------------------------------------------------------------
__global__ __launch_bounds__(256) void cayley_kernel(
    const float* __restrict__ Lsk, const float* __restrict__ Rsk,
    float* __restrict__ QL, float* __restrict__ QR)
{
    __shared__ float Ms[16][17];
    __shared__ float Rh[16][17];
    const int m = blockIdx.x;
    const float* src = (m < 16) ? (Lsk + m * 256) : (Rsk + (m - 16) * 256);
    const int t = threadIdx.x;
    const int i = t >> 4, j = t & 15;
    float a = src[i * 16 + j] - src[j * 16 + i];
    float eye = (i == j) ? 1.f : 0.f;
    Ms[i][j] = eye + a;
    Rh[i][j] = eye - a;
    __syncthreads();
    for (int k = 0; k < 16; ++k) {
        float f = Ms[i][k] / Ms[k][k];
        __syncthreads();
        if (i != k) {
            Ms[i][j] -= f * Ms[k][j];
            Rh[i][j] -= f * Rh[k][j];
        }
        __syncthreads();
    }
    float q = Rh[i][j] / Ms[i][i];
    float* dst = (m < 16) ? (QL + m * 256) : (QR + (m - 16) * 256);
    dst[i * 16 + j] = q;
}

// ---------------------------------------------------------------------------
// rmsnorm: out_bf16 = bf16(w * in / rms), fp32 input (used for both norms)
// ---------------------------------------------------------------------------
__global__ __launch_bounds__(256) void rms_kernel(
    const float* __restrict__ xin, const float* __restrict__ nw,
    ushort* __restrict__ xo)
{
    __shared__ float part[4];
    __shared__ float invs;
    const int row = blockIdx.x, t = threadIdx.x;
    float4 xv = *(const float4*)(xin + (size_t)row * DIM + t * 4);
    float ss = xv.x * xv.x + xv.y * xv.y + xv.z * xv.z + xv.w * xv.w;
    for (int off = 32; off > 0; off >>= 1) ss += __shfl_down(ss, off, 64);
    if ((t & 63) == 0) part[t >> 6] = ss;
    __syncthreads();
    if (t == 0) {
        float tot = part[0] + part[1] + part[2] + part[3];
        invs = 1.f / sqrtf(tot / (float)DIM + 1e-6f);
    }
    __syncthreads();
    float inv = invs;
    float4 wv = *(const float4*)(nw + t * 4);
    ushort4 ov;
    ov.x = f2bf(wv.x * xv.x * inv);
    ov.y = f2bf(wv.y * xv.y * inv);
    ov.z = f2bf(wv.z * xv.z * inv);
    ov.w = f2bf(wv.w * xv.w * inv);
    *(ushort4*)(xo + (size_t)row * DIM + t * 4) = ov;
}

// ---------------------------------------------------------------------------
// Windowed parallel scan. LC=16 -> 512 blocks = 2/CU (r4: -22us).
// r5: ONE barrier/step (was 2). Hs dependency is intra-wave only (thread
// (hi,lo) reads Hs[hi*16+k], written by its own 16-thread group inside one
// wave64 -> program order suffices). Us transpose-read crosses waves ->
// needs the barrier; Us double-buffered to kill the WAR race across the
// single barrier. Raw lgkmcnt(0)+s_barrier instead of __syncthreads: no
// vmcnt(0) drain, so the alpha/beta/bx prefetch and the hb global store
// stay in flight across steps.
// ---------------------------------------------------------------------------
__global__ __launch_bounds__(256) void scan_win_kernel(
    const float* __restrict__ QL, const float* __restrict__ QR,
    const float* __restrict__ gates, const float* __restrict__ Bx,
    ushort* __restrict__ hs)
{
    __shared__ float Hs[256];
    __shared__ float Us[2][256];
    const int chunk = blockIdx.x, b = blockIdx.y, t = threadIdx.x;
    const int hi = t >> 4, lo = t & 15;
    float Rrow[16], Lrow[16];
    #pragma unroll
    for (int k = 0; k < 16; ++k) {
        Rrow[k] = QR[hi * 256 + lo * 16 + k];   // R_Q[j=hi][i=lo][k]
        Lrow[k] = QL[lo * 256 + hi * 16 + k];   // L_Q[c=lo][r=hi][k]
    }
    Hs[t] = 0.f;
    __syncthreads();
    const int wstart = chunk * LC;
    const int s0 = (wstart >= WARM) ? (wstart - WARM) : 0;
    const int send = wstart + LC;
    const float* gb = gates + (size_t)b * S_LEN * 32;
    const float* xb = Bx + (size_t)b * S_LEN * NSTATE;
    ushort* hb = hs + (size_t)b * S_LEN * NSTATE;
    float beta  = gb[s0 * 32 + 16 + hi];
    float alpha = gb[s0 * 32 + lo];
    float bx    = xb[s0 * NSTATE + t];
    int q = 0;
    for (int s = s0; s < send; ++s) {
        float betaN = 0.f, alphaN = 0.f, bxN = 0.f;
        if (s + 1 < send) {
            betaN  = gb[(s + 1) * 32 + 16 + hi];
            alphaN = gb[(s + 1) * 32 + lo];
            bxN    = xb[(s + 1) * NSTATE + t];
        }
        float acc = 0.f;
        #pragma unroll
        for (int k = 0; k < 16; ++k) acc += Rrow[k] * Hs[hi * 16 + k];
        Us[q][t] = beta * acc;
        asm volatile("s_waitcnt lgkmcnt(0)" ::: "memory");
        __builtin_amdgcn_s_barrier();
        asm volatile("" ::: "memory");
        float acc2 = 0.f;
        #pragma unroll
        for (int k = 0; k < 16; ++k) acc2 += Lrow[k] * Us[q][k * 16 + lo];
        float h = alpha * acc2 + bx;
        Hs[t] = h;                       // intra-wave consumers only
        if (s >= wstart) hb[s * NSTATE + t] = f2bf(h);
        beta = betaN; alpha = alphaN; bx = bxN;
        q ^= 1;
    }
}

// ---------------------------------------------------------------------------
// Async GEMM: C(MxN) = A(MxK)*B(NxK)^T [+bias +resF] -> fp32.
// 128x128 tile, BK=64, XOR-8 LDS swizzle, 4 waves (2x2 of 64x64),
// 16x16x32 bf16 MFMA, global_load_lds width-16 staging.
// M,N % 128 == 0, K % 64 == 0, lda/ldb % 8 == 0 (callers pad).
// ---------------------------------------------------------------------------
__global__ __launch_bounds__(256) void gemm_async(
    const ushort* __restrict__ A, int lda,
    const ushort* __restrict__ B, int ldb,
    int K, int ldc,
    const float* __restrict__ bias,
    const float* __restrict__ resF,
    float* __restrict__ outF)
{
    __shared__ ushort As[128 * 64];
    __shared__ ushort Bs[128 * 64];
    const int tid = threadIdx.x;
    const int m0 = blockIdx.y * 128, n0 = blockIdx.x * 128;
    const int w = tid >> 6, lane = tid & 63;
    const int wm = (w >> 1) * 64, wn = (w & 1) * 64;
    const int lr = lane & 15, quad = lane >> 4;
    const int rx = lr & 7;   // reader XOR key (row&7 of every frag row)
    f32x4 acc[4][4];
    #pragma unroll
    for (int i = 0; i < 4; ++i)
        #pragma unroll
        for (int j = 0; j < 4; ++j) acc[i][j] = (f32x4){0.f, 0.f, 0.f, 0.f};
    const int srow = tid >> 3;                              // 0..31
    const int scol = (((tid & 7) ^ (srow & 7)) * 8);        // swizzled fetch col
    const ushort* ga = A + (size_t)(m0 + srow) * lda + scol;
    const ushort* gb = B + (size_t)(n0 + srow) * ldb + scol;
    for (int kt = 0; kt < K; kt += 64) {
        #pragma unroll
        for (int p = 0; p < 4; ++p) {
            gld_lds16(ga + (size_t)(p * 32) * lda + kt, &As[p * 2048 + tid * 8]);
            gld_lds16(gb + (size_t)(p * 32) * ldb + kt, &Bs[p * 2048 + tid * 8]);
        }
        __syncthreads();
        #pragma unroll
        for (int s = 0; s < 2; ++s) {
            const int cg = ((s * 4 + quad) ^ rx) * 8;
            bf16x8 af[4], bfr[4];
            #pragma unroll
            for (int f = 0; f < 4; ++f) {
                af[f]  = *(const bf16x8*)&As[(wm + f * 16 + lr) * 64 + cg];
                bfr[f] = *(const bf16x8*)&Bs[(wn + f * 16 + lr) * 64 + cg];
            }
            #pragma unroll
            for (int i = 0; i < 4; ++i)
                #pragma unroll
                for (int j = 0; j < 4; ++j)
                    acc[i][j] = __builtin_amdgcn_mfma_f32_16x16x32_bf16(
                        af[i], bfr[j], acc[i][j], 0, 0, 0);
        }
        __syncthreads();
    }
    #pragma unroll
    for (int i = 0; i < 4; ++i) {
        int row = m0 + wm + i * 16 + quad * 4;
        #pragma unroll
        for (int j = 0; j < 4; ++j) {
            int col = n0 + wn + j * 16 + lr;
            float bv = bias ? bias[col] : 0.f;
            #pragma unroll
            for (int r = 0; r < 4; ++r) {
                size_t idx = (size_t)(row + r) * ldc + col;
                float v = acc[i][j][r] + bv;
                if (resF) v += resF[idx];
                outF[idx] = v;
            }
        }
    }
}

// ---------------------------------------------------------------------------
// Merged Bx+gates GEMM: [Bx | gate-logits] = xs @ WBG^T, N=384, BK=64+swizzle.
// Epilogue: cols <256 -> Bx=v+bB (fp32); cols 256..287 -> gates=sigmoid(v+bg).
// ---------------------------------------------------------------------------
__global__ __launch_bounds__(256) void gemm_bxg(
    const ushort* __restrict__ A,     // xs: NROWS x DIM
    const ushort* __restrict__ WBG,   // NBG x DIM
    const float* __restrict__ bB, const float* __restrict__ bg,
    float* __restrict__ Bx, float* __restrict__ gates)
{
    __shared__ ushort As[128 * 64];
    __shared__ ushort Bs[128 * 64];
    const int tid = threadIdx.x;
    const int m0 = blockIdx.y * 128, n0 = blockIdx.x * 128;
    const int w = tid >> 6, lane = tid & 63;
    const int wm = (w >> 1) * 64, wn = (w & 1) * 64;
    const int lr = lane & 15, quad = lane >> 4;
    const int rx = lr & 7;
    f32x4 acc[4][4];
    #pragma unroll
    for (int i = 0; i < 4; ++i)
        #pragma unroll
        for (int j = 0; j < 4; ++j) acc[i][j] = (f32x4){0.f, 0.f, 0.f, 0.f};
    const int srow = tid >> 3;
    const int scol = (((tid & 7) ^ (srow & 7)) * 8);
    const ushort* ga = A   + (size_t)(m0 + srow) * DIM + scol;
    const ushort* gb = WBG + (size_t)(n0 + srow) * DIM + scol;
    for (int kt = 0; kt < DIM; kt += 64) {
        #pragma unroll
        for (int p = 0; p < 4; ++p) {
            gld_lds16(ga + (size_t)(p * 32) * DIM + kt, &As[p * 2048 + tid * 8]);
            gld_lds16(gb + (size_t)(p * 32) * DIM + kt, &Bs[p * 2048 + tid * 8]);
        }
        __syncthreads();
        #pragma unroll
        for (int s = 0; s < 2; ++s) {
            const int cg = ((s * 4 + quad) ^ rx) * 8;
            bf16x8 af[4], bfr[4];
            #pragma unroll
            for (int f = 0; f < 4; ++f) {
                af[f]  = *(const bf16x8*)&As[(wm + f * 16 + lr) * 64 + cg];
                bfr[f] = *(const bf16x8*)&Bs[(wn + f * 16 + lr) * 64 + cg];
            }
            #pragma unroll
            for (int i = 0; i < 4; ++i)
                #pragma unroll
                for (int j = 0; j < 4; ++j)
                    acc[i][j] = __builtin_amdgcn_mfma_f32_16x16x32_bf16(
                        af[i], bfr[j], acc[i][j], 0, 0, 0);
        }
        __syncthreads();
    }
    #pragma unroll
    for (int i = 0; i < 4; ++i) {
        int row = m0 + wm + i * 16 + quad * 4;
        #pragma unroll
        for (int j = 0; j < 4; ++j) {
            int col = n0 + wn + j * 16 + lr;
            #pragma unroll
            for (int r = 0; r < 4; ++r) {
                float v = acc[i][j][r];
                if (col < NSTATE) {
                    Bx[(size_t)(row + r) * NSTATE + col] = v + bB[col];
                } else if (col < NSTATE + 32) {
                    int g = col - NSTATE;
                    gates[(size_t)(row + r) * 32 + g] =
                        1.f / (1.f + expf(-(v + bg[g])));
                }
            }
        }
    }
}

// ---------------------------------------------------------------------------
// Fused FFN GEMM: pb = bf16( silu(xn@w1^T) * (xn@w2^T) ), K-padded layout.
// BK=64 + XOR-8 swizzle; A staged once, two B tiles -> 64 MFMA per barrier
// round. [r5 journal: 8-phase 256^2 abandoned after 3 attempts: r2 remat
// 184us, r3 spills 206us, r5 clean-but-LDS/barrier-bound 177us. This
// 2-barrier structure at 110us/860TF is its structural ceiling (m97-class);
// implicit 3-block/CU overlap already captures the pipeline gain.]
// ---------------------------------------------------------------------------
__global__ __launch_bounds__(256, 2) void ffn_gemm(
    const ushort* __restrict__ A,    // xn: NROWS x DIM
    const ushort* __restrict__ B1,   // w1p: DFQ x DIM
    const ushort* __restrict__ B2,   // w2p: DFQ x DIM
    ushort* __restrict__ pb)         // NROWS x DFFP
{
    __shared__ ushort As [128 * 64];
    __shared__ ushort B1s[128 * 64];
    __shared__ ushort B2s[128 * 64];
    const int tid = threadIdx.x;
    const int m0 = blockIdx.y * 128, n0 = blockIdx.x * 128;
    const int w = tid >> 6, lane = tid & 63;
    const int wm = (w >> 1) * 64, wn = (w & 1) * 64;
    const int lr = lane & 15, quad = lane >> 4;
    const int rx = lr & 7;
    f32x4 acc1[4][4], acc2[4][4];
    #pragma unroll
    for (int i = 0; i < 4; ++i)
        #pragma unroll
        for (int j = 0; j < 4; ++j) {
            acc1[i][j] = (f32x4){0.f, 0.f, 0.f, 0.f};
            acc2[i][j] = (f32x4){0.f, 0.f, 0.f, 0.f};
        }
    const int srow = tid >> 3;
    const int scol = (((tid & 7) ^ (srow & 7)) * 8);
    const ushort* ga  = A  + (size_t)(m0 + srow) * DIM + scol;
    const ushort* gb1 = B1 + (size_t)(n0 + srow) * DIM + scol;
    const ushort* gb2 = B2 + (size_t)(n0 + srow) * DIM + scol;
    for (int kt = 0; kt < DIM; kt += 64) {
        #pragma unroll
        for (int p = 0; p < 4; ++p) {
            gld_lds16(ga  + (size_t)(p * 32) * DIM + kt, &As [p * 2048 + tid * 8]);
            gld_lds16(gb1 + (size_t)(p * 32) * DIM + kt, &B1s[p * 2048 + tid * 8]);
            gld_lds16(gb2 + (size_t)(p * 32) * DIM + kt, &B2s[p * 2048 + tid * 8]);
        }
        __syncthreads();
        #pragma unroll
        for (int s = 0; s < 2; ++s) {
            const int cg = ((s * 4 + quad) ^ rx) * 8;
            bf16x8 af[4], b1f[4], b2f[4];
            #pragma unroll
            for (int f = 0; f < 4; ++f) {
                af[f]  = *(const bf16x8*)&As [(wm + f * 16 + lr) * 64 + cg];
                b1f[f] = *(const bf16x8*)&B1s[(wn + f * 16 + lr) * 64 + cg];
                b2f[f] = *(const bf16x8*)&B2s[(wn + f * 16 + lr) * 64 + cg];
            }
            #pragma unroll
            for (int i = 0; i < 4; ++i)
                #pragma unroll
                for (int j = 0; j < 4; ++j) {
                    acc1[i][j] = __builtin_amdgcn_mfma_f32_16x16x32_bf16(
                        af[i], b1f[j], acc1[i][j], 0, 0, 0);
                    acc2[i][j] = __builtin_amdgcn_mfma_f32_16x16x32_bf16(
                        af[i], b2f[j], acc2[i][j], 0, 0, 0);
                }
        }
        __syncthreads();
    }
    #pragma unroll
    for (int i = 0; i < 4; ++i) {
        int row = m0 + wm + i * 16 + quad * 4;
        #pragma unroll
        for (int j = 0; j < 4; ++j) {
            int col = n0 + wn + j * 16 + lr;
            if (col < DFFP) {
                #pragma unroll
                for (int r = 0; r < 4; ++r) {
                    float v1 = acc1[i][j][r];
                    float v2 = acc2[i][j][r];
                    float p = v1 / (1.f + expf(-v1)) * v2;
                    pb[(size_t)(row + r) * DFFP + col] = f2bf(p);
                }
            }
        }
    }
}

// ---------------------------------------------------------------------------
extern "C" void kernel_launch(void* const* d_in, const int* in_sizes, int n_in,
                              void* d_out, int out_size, void* d_ws, size_t ws_size,
                              hipStream_t stream) {
    const float* x   = (const float*)d_in[0];
    const float* Lsk = (const float*)d_in[1];
    const float* Rsk = (const float*)d_in[2];
    const float* Wg  = (const float*)d_in[3];
    const float* bg  = (const float*)d_in[4];
    const float* WB  = (const float*)d_in[5];
    const float* bB  = (const float*)d_in[6];
    const float* WC  = (const float*)d_in[7];
    const float* bC  = (const float*)d_in[8];
    const float* n1w = (const float*)d_in[9];
    const float* n2w = (const float*)d_in[10];
    const float* w1  = (const float*)d_in[11];
    const float* w2  = (const float*)d_in[12];
    const float* w3  = (const float*)d_in[13];
    float* out = (float*)d_out;

    char* wp = (char*)d_ws;
    auto carve = [&](size_t bytes) -> char* {
        char* p = wp;
        wp += (bytes + 255) & ~(size_t)255;
        return p;
    };
    float*  QL    = (float*)carve(16 * 256 * 4);
    float*  QR    = (float*)carve(16 * 256 * 4);
    ushort* WBGb  = (ushort*)carve((size_t)NBG * DIM * 2);
    ushort* WCb   = (ushort*)carve((size_t)DIM * NSTATE * 2);
    ushort* w1p   = (ushort*)carve((size_t)DFQ * DIM * 2);
    ushort* w2p   = (ushort*)carve((size_t)DFQ * DIM * 2);
    ushort* w3p   = (ushort*)carve((size_t)DIM * DFFP * 2);
    ushort* xs    = (ushort*)carve((size_t)NROWS * DIM * 2);
    float*  x2    = (float*)carve((size_t)NROWS * DIM * 4);
    ushort* pb    = (ushort*)carve((size_t)NROWS * DFFP * 2);
    char*   scr   = carve((size_t)16 << 20);                // gates/Bx/hs region
    float*  gates = (float*)scr;                            // 1.05 MB
    float*  Bx    = (float*)(scr + (1 << 21));              // 8.39 MB @ +2MB
    ushort* hs    = (ushort*)(scr + (11u << 20));           // 4.19 MB @ +11MB
    ushort* xn    = xs;   // xs dead after bxg GEMM; reuse as xn

    cayley_kernel<<<32, 256, 0, stream>>>(Lsk, Rsk, QL, QR);
    pack_wbg_kernel<<<NBG, 256, 0, stream>>>(WB, Wg, WBGb);
    f2b_kernel<<<256, 256, 0, stream>>>(WC, WCb, DIM * NSTATE / 4);
    f2b_padrow_kernel<<<DFQ, 256, 0, stream>>>(w1, w1p, DFF);
    f2b_padrow_kernel<<<DFQ, 256, 0, stream>>>(w2, w2p, DFF);
    pad_w3_kernel<<<dim3(11, DIM), 256, 0, stream>>>(w3, w3p);
    // xs = rmsnorm(x, n1w)
    rms_kernel<<<NROWS, 256, 0, stream>>>(x, n1w, xs);
    // [Bx | gates] = xs @ WBG^T (+bB | sigmoid(+bg))
    gemm_bxg<<<dim3(3, 64), 256, 0, stream>>>(xs, WBGb, bB, bg, Bx, gates);
    scan_win_kernel<<<dim3(S_LEN / LC, BATCH), 256, 0, stream>>>(QL, QR, gates, Bx, hs);
    // x2 = hs @ WC^T + bC + x  -> fp32
    gemm_async<<<dim3(8, 64), 256, 0, stream>>>(hs, NSTATE, WCb, NSTATE, NSTATE, DIM,
                                                bC, x, x2);
    // xn = rmsnorm(x2, n2w)
    rms_kernel<<<NROWS, 256, 0, stream>>>(x2, n2w, xn);
    // pb = silu(xn@w1^T) * (xn@w2^T)  (fused, K-padded bf16 out)
    ffn_gemm<<<dim3(DFQ / 128, 64), 256, 0, stream>>>(xn, w1p, w2p, pb);
    // out = pb @ w3p^T + x2  -> fp32 (d_out)
    gemm_async<<<dim3(8, 64), 256, 0, stream>>>(pb, DFFP, w3p, DFFP, DFFP, DIM,
                                                nullptr, x2, out);
}

// Round 7
// 414.037 us; speedup vs baseline: 1.1588x; 1.0405x over previous
//
#include <hip/hip_runtime.h>
#include <hip/hip_bf16.h>

#define S_LEN  2048
#define BATCH  4
#define DIM    1024
#define NSTATE 256
#define DFF    2730
#define DFFP   2752              // K-padding for final GEMM (mult of 64)
#define DFQ    2816              // row-padding for w1/w2 (mult of 128)
#define NROWS  (BATCH * S_LEN)   // 8192
#define LC     16                // scan chunk length (r4 win: 2 blocks/CU)
#define WARM   32                // scan warm-up window (decay ~e^-13 worst)
#define NBG    384               // WB(256) + Wg(32) + zero pad(96)

// prep_kernel block-range offsets (r6: fuse 7 launches into 1)
#define PB_CAYLEY 0                         // 32 blocks
#define PB_WBG    (PB_CAYLEY + 32)          // 384
#define PB_WC     (PB_WBG + NBG)            // 256
#define PB_W1     (PB_WC + 256)             // 2816
#define PB_W2     (PB_W1 + DFQ)             // 2816
#define PB_W3     (PB_W2 + DFQ)             // 11264
#define PB_RMS    (PB_W3 + 11 * DIM)        // 8192
#define PB_TOTAL  (PB_RMS + NROWS)          // 25760

typedef __attribute__((ext_vector_type(8))) short bf16x8;
typedef __attribute__((ext_vector_type(4))) float f32x4;

__device__ __forceinline__ float bf2f(ushort u) {
    return __uint_as_float(((unsigned int)u) << 16);
}
__device__ __forceinline__ ushort f2bf(float f) {
    unsigned int u = __float_as_uint(f);
    u += 0x7fffu + ((u >> 16) & 1u);   // RNE
    return (ushort)(u >> 16);
}

// async global->LDS, 16B per lane. LDS dest is wave-uniform base + lane*16.
__device__ __forceinline__ void gld_lds16(const ushort* g, ushort* l) {
    __builtin_amdgcn_global_load_lds(
        (const __attribute__((address_space(1))) unsigned int*)g,
        (__attribute__((address_space(3))) unsigned int*)l,
        16, 0, 0);
}

// ---------------------------------------------------------------------------
// Unified prep kernel: cayley | pack_wbg | f2b(WC) | padrow(w1) | padrow(w2)
// | pad_w3 | rmsnorm1. All branches are the verbatim former kernel bodies
// with remapped block indices; blocks take exactly one branch (no intra-block
// divergence). 13 -> 7 total launches in the pipeline.
// ---------------------------------------------------------------------------
__global__ __launch_bounds__(256) void prep_kernel(
    const float* __restrict__ Lsk, const float* __restrict__ Rsk,
    float* __restrict__ QL, float* __restrict__ QR,
    const float* __restrict__ WB, const float* __restrict__ Wg,
    ushort* __restrict__ WBGb,
    const float* __restrict__ WC, ushort* __restrict__ WCb,
    const float* __restrict__ w1, ushort* __restrict__ w1p,
    const float* __restrict__ w2, ushort* __restrict__ w2p,
    const float* __restrict__ w3, ushort* __restrict__ w3p,
    const float* __restrict__ x, const float* __restrict__ n1w,
    ushort* __restrict__ xs)
{
    const int bid = blockIdx.x, t = threadIdx.x;

    if (bid < PB_WBG) {                       // ---- cayley (32 blocks)
        __shared__ float Ms[16][17];
        __shared__ float Rh[16][17];
        const int m = bid;
        const float* src = (m < 16) ? (Lsk + m * 256) : (Rsk + (m - 16) * 256);
        const int i = t >> 4, j = t & 15;
        float a = src[i * 16 + j] - src[j * 16 + i];
        float eye = (i == j) ? 1.f : 0.f;
        Ms[i][j] = eye + a;
        Rh[i][j] = eye - a;
        __syncthreads();
        for (int k = 0; k < 16; ++k) {
            float f = Ms[i][k] / Ms[k][k];
            __syncthreads();
            if (i != k) {
                Ms[i][j] -= f * Ms[k][j];
                Rh[i][j] -= f * Rh[k][j];
            }
            __syncthreads();
        }
        float q = Rh[i][j] / Ms[i][i];
        float* dst = (m < 16) ? (QL + m * 256) : (QR + (m - 16) * 256);
        dst[i * 16 + j] = q;
    } else if (bid < PB_WC) {                 // ---- pack_wbg (384 blocks)
        const int row = bid - PB_WBG;
        ushort4 o = {0, 0, 0, 0};
        const float* src = nullptr;
        if (row < NSTATE) src = WB + (size_t)row * DIM;
        else if (row < NSTATE + 32) src = Wg + (size_t)(row - NSTATE) * DIM;
        if (src) {
            float4 v = *(const float4*)(src + t * 4);
            o.x = f2bf(v.x); o.y = f2bf(v.y); o.z = f2bf(v.z); o.w = f2bf(v.w);
        }
        *(ushort4*)(WBGb + (size_t)row * DIM + t * 4) = o;
    } else if (bid < PB_W1) {                 // ---- f2b WC (256 blocks)
        const int i = (bid - PB_WC) * 256 + t;     // covers DIM*NSTATE/4 exactly
        float4 v = *(const float4*)(WC + i * 4);
        ushort4 o;
        o.x = f2bf(v.x); o.y = f2bf(v.y); o.z = f2bf(v.z); o.w = f2bf(v.w);
        *(ushort4*)(WCb + i * 4) = o;
    } else if (bid < PB_W2) {                 // ---- padrow w1 (2816 blocks)
        const int row = bid - PB_W1;
        ushort4 o = {0, 0, 0, 0};
        if (row < DFF) {
            float4 v = *(const float4*)(w1 + (size_t)row * DIM + t * 4);
            o.x = f2bf(v.x); o.y = f2bf(v.y); o.z = f2bf(v.z); o.w = f2bf(v.w);
        }
        *(ushort4*)(w1p + (size_t)row * DIM + t * 4) = o;
    } else if (bid < PB_W3) {                 // ---- padrow w2 (2816 blocks)
        const int row = bid - PB_W2;
        ushort4 o = {0, 0, 0, 0};
        if (row < DFF) {
            float4 v = *(const float4*)(w2 + (size_t)row * DIM + t * 4);
            o.x = f2bf(v.x); o.y = f2bf(v.y); o.z = f2bf(v.z); o.w = f2bf(v.w);
        }
        *(ushort4*)(w2p + (size_t)row * DIM + t * 4) = o;
    } else if (bid < PB_RMS) {                // ---- pad_w3 (11264 blocks)
        const int lid = bid - PB_W3;
        const int row = lid / 11, cb = lid % 11;
        const int col = cb * 256 + t;
        if (col < DFFP) {
            ushort v = 0;
            if (col < DFF) v = f2bf(w3[(size_t)row * DFF + col]);
            w3p[(size_t)row * DFFP + col] = v;
        }
    } else {                                  // ---- rmsnorm1 (8192 blocks)
        __shared__ float part[4];
        __shared__ float invs;
        const int row = bid - PB_RMS;
        float4 xv = *(const float4*)(x + (size_t)row * DIM + t * 4);
        float ss = xv.x * xv.x + xv.y * xv.y + xv.z * xv.z + xv.w * xv.w;
        for (int off = 32; off > 0; off >>= 1) ss += __shfl_down(ss, off, 64);
        if ((t & 63) == 0) part[t >> 6] = ss;
        __syncthreads();
        if (t == 0) {
            float tot = part[0] + part[1] + part[2] + part[3];
            invs = 1.f / sqrtf(tot / (float)DIM + 1e-6f);
        }
        __syncthreads();
        float inv = invs;
        float4 wv = *(const float4*)(n1w + t * 4);
        ushort4 ov;
        ov.x = f2bf(wv.x * xv.x * inv);
        ov.y = f2bf(wv.y * xv.y * inv);
        ov.z = f2bf(wv.z * xv.z * inv);
        ov.w = f2bf(wv.w * xv.w * inv);
        *(ushort4*)(xs + (size_t)row * DIM + t * 4) = ov;
    }
}

// ---------------------------------------------------------------------------
// rmsnorm: out_bf16 = bf16(w * in / rms), fp32 input (norm2 only now)
// ---------------------------------------------------------------------------
__global__ __launch_bounds__(256) void rms_kernel(
    const float* __restrict__ xin, const float* __restrict__ nw,
    ushort* __restrict__ xo)
{
    __shared__ float part[4];
    __shared__ float invs;
    const int row = blockIdx.x, t = threadIdx.x;
    float4 xv = *(const float4*)(xin + (size_t)row * DIM + t * 4);
    float ss = xv.x * xv.x + xv.y * xv.y + xv.z * xv.z + xv.w * xv.w;
    for (int off = 32; off > 0; off >>= 1) ss += __shfl_down(ss, off, 64);
    if ((t & 63) == 0) part[t >> 6] = ss;
    __syncthreads();
    if (t == 0) {
        float tot = part[0] + part[1] + part[2] + part[3];
        invs = 1.f / sqrtf(tot / (float)DIM + 1e-6f);
    }
    __syncthreads();
    float inv = invs;
    float4 wv = *(const float4*)(nw + t * 4);
    ushort4 ov;
    ov.x = f2bf(wv.x * xv.x * inv);
    ov.y = f2bf(wv.y * xv.y * inv);
    ov.z = f2bf(wv.z * xv.z * inv);
    ov.w = f2bf(wv.w * xv.w * inv);
    *(ushort4*)(xo + (size_t)row * DIM + t * 4) = ov;
}

// ---------------------------------------------------------------------------
// Windowed parallel scan. LC=16 -> 512 blocks = 2/CU (r4: -22us).
// One barrier/step (r5, neutral but kept): Hs deps are intra-wave; Us
// double-buffered; raw lgkmcnt+s_barrier avoids the vmcnt(0) drain.
// ---------------------------------------------------------------------------
__global__ __launch_bounds__(256) void scan_win_kernel(
    const float* __restrict__ QL, const float* __restrict__ QR,
    const float* __restrict__ gates, const float* __restrict__ Bx,
    ushort* __restrict__ hs)
{
    __shared__ float Hs[256];
    __shared__ float Us[2][256];
    const int chunk = blockIdx.x, b = blockIdx.y, t = threadIdx.x;
    const int hi = t >> 4, lo = t & 15;
    float Rrow[16], Lrow[16];
    #pragma unroll
    for (int k = 0; k < 16; ++k) {
        Rrow[k] = QR[hi * 256 + lo * 16 + k];   // R_Q[j=hi][i=lo][k]
        Lrow[k] = QL[lo * 256 + hi * 16 + k];   // L_Q[c=lo][r=hi][k]
    }
    Hs[t] = 0.f;
    __syncthreads();
    const int wstart = chunk * LC;
    const int s0 = (wstart >= WARM) ? (wstart - WARM) : 0;
    const int send = wstart + LC;
    const float* gb = gates + (size_t)b * S_LEN * 32;
    const float* xb = Bx + (size_t)b * S_LEN * NSTATE;
    ushort* hb = hs + (size_t)b * S_LEN * NSTATE;
    float beta  = gb[s0 * 32 + 16 + hi];
    float alpha = gb[s0 * 32 + lo];
    float bx    = xb[s0 * NSTATE + t];
    int q = 0;
    for (int s = s0; s < send; ++s) {
        float betaN = 0.f, alphaN = 0.f, bxN = 0.f;
        if (s + 1 < send) {
            betaN  = gb[(s + 1) * 32 + 16 + hi];
            alphaN = gb[(s + 1) * 32 + lo];
            bxN    = xb[(s + 1) * NSTATE + t];
        }
        float acc = 0.f;
        #pragma unroll
        for (int k = 0; k < 16; ++k) acc += Rrow[k] * Hs[hi * 16 + k];
        Us[q][t] = beta * acc;
        asm volatile("s_waitcnt lgkmcnt(0)" ::: "memory");
        __builtin_amdgcn_s_barrier();
        asm volatile("" ::: "memory");
        float acc2 = 0.f;
        #pragma unroll
        for (int k = 0; k < 16; ++k) acc2 += Lrow[k] * Us[q][k * 16 + lo];
        float h = alpha * acc2 + bx;
        Hs[t] = h;                       // intra-wave consumers only
        if (s >= wstart) hb[s * NSTATE + t] = f2bf(h);
        beta = betaN; alpha = alphaN; bx = bxN;
        q ^= 1;
    }
}

// ---------------------------------------------------------------------------
// Async GEMM: C(MxN) = A(MxK)*B(NxK)^T [+bias +resF] -> fp32.
// 128x128 tile, BK=64, XOR-8 LDS swizzle, 4 waves (2x2 of 64x64),
// 16x16x32 bf16 MFMA, global_load_lds width-16 staging.
// ---------------------------------------------------------------------------
__global__ __launch_bounds__(256) void gemm_async(
    const ushort* __restrict__ A, int lda,
    const ushort* __restrict__ B, int ldb,
    int K, int ldc,
    const float* __restrict__ bias,
    const float* __restrict__ resF,
    float* __restrict__ outF)
{
    __shared__ ushort As[128 * 64];
    __shared__ ushort Bs[128 * 64];
    const int tid = threadIdx.x;
    const int m0 = blockIdx.y * 128, n0 = blockIdx.x * 128;
    const int w = tid >> 6, lane = tid & 63;
    const int wm = (w >> 1) * 64, wn = (w & 1) * 64;
    const int lr = lane & 15, quad = lane >> 4;
    const int rx = lr & 7;   // reader XOR key (row&7 of every frag row)
    f32x4 acc[4][4];
    #pragma unroll
    for (int i = 0; i < 4; ++i)
        #pragma unroll
        for (int j = 0; j < 4; ++j) acc[i][j] = (f32x4){0.f, 0.f, 0.f, 0.f};
    const int srow = tid >> 3;                              // 0..31
    const int scol = (((tid & 7) ^ (srow & 7)) * 8);        // swizzled fetch col
    const ushort* ga = A + (size_t)(m0 + srow) * lda + scol;
    const ushort* gb = B + (size_t)(n0 + srow) * ldb + scol;
    for (int kt = 0; kt < K; kt += 64) {
        #pragma unroll
        for (int p = 0; p < 4; ++p) {
            gld_lds16(ga + (size_t)(p * 32) * lda + kt, &As[p * 2048 + tid * 8]);
            gld_lds16(gb + (size_t)(p * 32) * ldb + kt, &Bs[p * 2048 + tid * 8]);
        }
        __syncthreads();
        #pragma unroll
        for (int s = 0; s < 2; ++s) {
            const int cg = ((s * 4 + quad) ^ rx) * 8;
            bf16x8 af[4], bfr[4];
            #pragma unroll
            for (int f = 0; f < 4; ++f) {
                af[f]  = *(const bf16x8*)&As[(wm + f * 16 + lr) * 64 + cg];
                bfr[f] = *(const bf16x8*)&Bs[(wn + f * 16 + lr) * 64 + cg];
            }
            #pragma unroll
            for (int i = 0; i < 4; ++i)
                #pragma unroll
                for (int j = 0; j < 4; ++j)
                    acc[i][j] = __builtin_amdgcn_mfma_f32_16x16x32_bf16(
                        af[i], bfr[j], acc[i][j], 0, 0, 0);
        }
        __syncthreads();
    }
    #pragma unroll
    for (int i = 0; i < 4; ++i) {
        int row = m0 + wm + i * 16 + quad * 4;
        #pragma unroll
        for (int j = 0; j < 4; ++j) {
            int col = n0 + wn + j * 16 + lr;
            float bv = bias ? bias[col] : 0.f;
            #pragma unroll
            for (int r = 0; r < 4; ++r) {
                size_t idx = (size_t)(row + r) * ldc + col;
                float v = acc[i][j][r] + bv;
                if (resF) v += resF[idx];
                outF[idx] = v;
            }
        }
    }
}

// ---------------------------------------------------------------------------
// Merged Bx+gates GEMM: [Bx | gate-logits] = xs @ WBG^T, N=384, BK=64+swizzle.
// ---------------------------------------------------------------------------
__global__ __launch_bounds__(256) void gemm_bxg(
    const ushort* __restrict__ A,     // xs: NROWS x DIM
    const ushort* __restrict__ WBG,   // NBG x DIM
    const float* __restrict__ bB, const float* __restrict__ bg,
    float* __restrict__ Bx, float* __restrict__ gates)
{
    __shared__ ushort As[128 * 64];
    __shared__ ushort Bs[128 * 64];
    const int tid = threadIdx.x;
    const int m0 = blockIdx.y * 128, n0 = blockIdx.x * 128;
    const int w = tid >> 6, lane = tid & 63;
    const int wm = (w >> 1) * 64, wn = (w & 1) * 64;
    const int lr = lane & 15, quad = lane >> 4;
    const int rx = lr & 7;
    f32x4 acc[4][4];
    #pragma unroll
    for (int i = 0; i < 4; ++i)
        #pragma unroll
        for (int j = 0; j < 4; ++j) acc[i][j] = (f32x4){0.f, 0.f, 0.f, 0.f};
    const int srow = tid >> 3;
    const int scol = (((tid & 7) ^ (srow & 7)) * 8);
    const ushort* ga = A   + (size_t)(m0 + srow) * DIM + scol;
    const ushort* gb = WBG + (size_t)(n0 + srow) * DIM + scol;
    for (int kt = 0; kt < DIM; kt += 64) {
        #pragma unroll
        for (int p = 0; p < 4; ++p) {
            gld_lds16(ga + (size_t)(p * 32) * DIM + kt, &As[p * 2048 + tid * 8]);
            gld_lds16(gb + (size_t)(p * 32) * DIM + kt, &Bs[p * 2048 + tid * 8]);
        }
        __syncthreads();
        #pragma unroll
        for (int s = 0; s < 2; ++s) {
            const int cg = ((s * 4 + quad) ^ rx) * 8;
            bf16x8 af[4], bfr[4];
            #pragma unroll
            for (int f = 0; f < 4; ++f) {
                af[f]  = *(const bf16x8*)&As[(wm + f * 16 + lr) * 64 + cg];
                bfr[f] = *(const bf16x8*)&Bs[(wn + f * 16 + lr) * 64 + cg];
            }
            #pragma unroll
            for (int i = 0; i < 4; ++i)
                #pragma unroll
                for (int j = 0; j < 4; ++j)
                    acc[i][j] = __builtin_amdgcn_mfma_f32_16x16x32_bf16(
                        af[i], bfr[j], acc[i][j], 0, 0, 0);
        }
        __syncthreads();
    }
    #pragma unroll
    for (int i = 0; i < 4; ++i) {
        int row = m0 + wm + i * 16 + quad * 4;
        #pragma unroll
        for (int j = 0; j < 4; ++j) {
            int col = n0 + wn + j * 16 + lr;
            #pragma unroll
            for (int r = 0; r < 4; ++r) {
                float v = acc[i][j][r];
                if (col < NSTATE) {
                    Bx[(size_t)(row + r) * NSTATE + col] = v + bB[col];
                } else if (col < NSTATE + 32) {
                    int g = col - NSTATE;
                    gates[(size_t)(row + r) * 32 + g] =
                        1.f / (1.f + expf(-(v + bg[g])));
                }
            }
        }
    }
}

// ---------------------------------------------------------------------------
// Fused FFN GEMM: pb = bf16( silu(xn@w1^T) * (xn@w2^T) ), K-padded layout.
// BK=64 + XOR-8 swizzle; A staged once, two B tiles -> 64 MFMA per barrier
// round. [2-barrier structure = its structural ceiling at ~108us/875TF;
// 8-phase port abandoned after 3 attempts (r2 remat / r3 spills / r5
// LDS+barrier-bound).]
// ---------------------------------------------------------------------------
__global__ __launch_bounds__(256, 2) void ffn_gemm(
    const ushort* __restrict__ A,    // xn: NROWS x DIM
    const ushort* __restrict__ B1,   // w1p: DFQ x DIM
    const ushort* __restrict__ B2,   // w2p: DFQ x DIM
    ushort* __restrict__ pb)         // NROWS x DFFP
{
    __shared__ ushort As [128 * 64];
    __shared__ ushort B1s[128 * 64];
    __shared__ ushort B2s[128 * 64];
    const int tid = threadIdx.x;
    const int m0 = blockIdx.y * 128, n0 = blockIdx.x * 128;
    const int w = tid >> 6, lane = tid & 63;
    const int wm = (w >> 1) * 64, wn = (w & 1) * 64;
    const int lr = lane & 15, quad = lane >> 4;
    const int rx = lr & 7;
    f32x4 acc1[4][4], acc2[4][4];
    #pragma unroll
    for (int i = 0; i < 4; ++i)
        #pragma unroll
        for (int j = 0; j < 4; ++j) {
            acc1[i][j] = (f32x4){0.f, 0.f, 0.f, 0.f};
            acc2[i][j] = (f32x4){0.f, 0.f, 0.f, 0.f};
        }
    const int srow = tid >> 3;
    const int scol = (((tid & 7) ^ (srow & 7)) * 8);
    const ushort* ga  = A  + (size_t)(m0 + srow) * DIM + scol;
    const ushort* gb1 = B1 + (size_t)(n0 + srow) * DIM + scol;
    const ushort* gb2 = B2 + (size_t)(n0 + srow) * DIM + scol;
    for (int kt = 0; kt < DIM; kt += 64) {
        #pragma unroll
        for (int p = 0; p < 4; ++p) {
            gld_lds16(ga  + (size_t)(p * 32) * DIM + kt, &As [p * 2048 + tid * 8]);
            gld_lds16(gb1 + (size_t)(p * 32) * DIM + kt, &B1s[p * 2048 + tid * 8]);
            gld_lds16(gb2 + (size_t)(p * 32) * DIM + kt, &B2s[p * 2048 + tid * 8]);
        }
        __syncthreads();
        #pragma unroll
        for (int s = 0; s < 2; ++s) {
            const int cg = ((s * 4 + quad) ^ rx) * 8;
            bf16x8 af[4], b1f[4], b2f[4];
            #pragma unroll
            for (int f = 0; f < 4; ++f) {
                af[f]  = *(const bf16x8*)&As [(wm + f * 16 + lr) * 64 + cg];
                b1f[f] = *(const bf16x8*)&B1s[(wn + f * 16 + lr) * 64 + cg];
                b2f[f] = *(const bf16x8*)&B2s[(wn + f * 16 + lr) * 64 + cg];
            }
            #pragma unroll
            for (int i = 0; i < 4; ++i)
                #pragma unroll
                for (int j = 0; j < 4; ++j) {
                    acc1[i][j] = __builtin_amdgcn_mfma_f32_16x16x32_bf16(
                        af[i], b1f[j], acc1[i][j], 0, 0, 0);
                    acc2[i][j] = __builtin_amdgcn_mfma_f32_16x16x32_bf16(
                        af[i], b2f[j], acc2[i][j], 0, 0, 0);
                }
        }
        __syncthreads();
    }
    #pragma unroll
    for (int i = 0; i < 4; ++i) {
        int row = m0 + wm + i * 16 + quad * 4;
        #pragma unroll
        for (int j = 0; j < 4; ++j) {
            int col = n0 + wn + j * 16 + lr;
            if (col < DFFP) {
                #pragma unroll
                for (int r = 0; r < 4; ++r) {
                    float v1 = acc1[i][j][r];
                    float v2 = acc2[i][j][r];
                    float p = v1 / (1.f + expf(-v1)) * v2;
                    pb[(size_t)(row + r) * DFFP + col] = f2bf(p);
                }
            }
        }
    }
}

// ---------------------------------------------------------------------------
extern "C" void kernel_launch(void* const* d_in, const int* in_sizes, int n_in,
                              void* d_out, int out_size, void* d_ws, size_t ws_size,
                              hipStream_t stream) {
    const float* x   = (const float*)d_in[0];
    const float* Lsk = (const float*)d_in[1];
    const float* Rsk = (const float*)d_in[2];
    const float* Wg  = (const float*)d_in[3];
    const float* bg  = (const float*)d_in[4];
    const float* WB  = (const float*)d_in[5];
    const float* bB  = (const float*)d_in[6];
    const float* WC  = (const float*)d_in[7];
    const float* bC  = (const float*)d_in[8];
    const float* n1w = (const float*)d_in[9];
    const float* n2w = (const float*)d_in[10];
    const float* w1  = (const float*)d_in[11];
    const float* w2  = (const float*)d_in[12];
    const float* w3  = (const float*)d_in[13];
    float* out = (float*)d_out;

    char* wp = (char*)d_ws;
    auto carve = [&](size_t bytes) -> char* {
        char* p = wp;
        wp += (bytes + 255) & ~(size_t)255;
        return p;
    };
    float*  QL    = (float*)carve(16 * 256 * 4);
    float*  QR    = (float*)carve(16 * 256 * 4);
    ushort* WBGb  = (ushort*)carve((size_t)NBG * DIM * 2);
    ushort* WCb   = (ushort*)carve((size_t)DIM * NSTATE * 2);
    ushort* w1p   = (ushort*)carve((size_t)DFQ * DIM * 2);
    ushort* w2p   = (ushort*)carve((size_t)DFQ * DIM * 2);
    ushort* w3p   = (ushort*)carve((size_t)DIM * DFFP * 2);
    ushort* xs    = (ushort*)carve((size_t)NROWS * DIM * 2);
    float*  x2    = (float*)carve((size_t)NROWS * DIM * 4);
    ushort* pb    = (ushort*)carve((size_t)NROWS * DFFP * 2);
    char*   scr   = carve((size_t)16 << 20);                // gates/Bx/hs region
    float*  gates = (float*)scr;                            // 1.05 MB
    float*  Bx    = (float*)(scr + (1 << 21));              // 8.39 MB @ +2MB
    ushort* hs    = (ushort*)(scr + (11u << 20));           // 4.19 MB @ +11MB
    ushort* xn    = xs;   // xs dead after bxg GEMM; reuse as xn

    // all weight prep + cayley + rmsnorm1 in ONE launch (13 -> 7 launches)
    prep_kernel<<<PB_TOTAL, 256, 0, stream>>>(
        Lsk, Rsk, QL, QR, WB, Wg, WBGb, WC, WCb,
        w1, w1p, w2, w2p, w3, w3p, x, n1w, xs);
    // [Bx | gates] = xs @ WBG^T (+bB | sigmoid(+bg))
    gemm_bxg<<<dim3(3, 64), 256, 0, stream>>>(xs, WBGb, bB, bg, Bx, gates);
    scan_win_kernel<<<dim3(S_LEN / LC, BATCH), 256, 0, stream>>>(QL, QR, gates, Bx, hs);
    // x2 = hs @ WC^T + bC + x  -> fp32
    gemm_async<<<dim3(8, 64), 256, 0, stream>>>(hs, NSTATE, WCb, NSTATE, NSTATE, DIM,
                                                bC, x, x2);
    // xn = rmsnorm(x2, n2w)
    rms_kernel<<<NROWS, 256, 0, stream>>>(x2, n2w, xn);
    // pb = silu(xn@w1^T) * (xn@w2^T)  (fused, K-padded bf16 out)
    ffn_gemm<<<dim3(DFQ / 128, 64), 256, 0, stream>>>(xn, w1p, w2p, pb);
    // out = pb @ w3p^T + x2  -> fp32 (d_out)
    gemm_async<<<dim3(8, 64), 256, 0, stream>>>(pb, DFFP, w3p, DFFP, DFFP, DIM,
                                                nullptr, x2, out);
}